// Round 3
// baseline (230.447 us; speedup 1.0000x reference)
//
#include <hip/hip_runtime.h>

#define BB 8
#define NN 4096
#define CCH 512
#define KK 32
#define CLS 21
#define BN_EPS 1e-3f

#define TPB 512
#define CHUNK 64
#define NBLK (NN / CHUNK)   // 64 -> grid 512 blocks = 2/CU

typedef _Float16 f16;
typedef _Float16 half2v __attribute__((ext_vector_type(2)));
typedef _Float16 half4v __attribute__((ext_vector_type(4)));
typedef _Float16 half8v __attribute__((ext_vector_type(8)));
typedef float float2v __attribute__((ext_vector_type(2)));

// xn pitch in f16 units (1056 B, 16B-aligned)
#define XPH 528
#define WPH 40

// LDS carve (bytes): cwL 32768 | xn 33792 | wt 2560 | f32 tail 1408
#define SMB_CWL 0
#define SMB_XN  32768
#define SMB_WT  (SMB_XN + 32 * XPH * 2)      // 66560
#define SMB_F32 (SMB_WT + 32 * WPH * 2)      // 69120
#define SM_BYTES (SMB_F32 + (64 + 256 + 32) * 4)  // 70528

// ws layout (floats)
#define WS_WX   0
#define WS_WSUM (BB * CCH * KK)              // 131072
#define WS_ENC  (WS_WSUM + BB * KK)          // 131328
#define WS_ATTN (WS_ENC + BB * CCH)          // 135424

template <int CTRL>
__device__ __forceinline__ float dpp_add(float v) {
    int r = __builtin_amdgcn_update_dpp(0, __builtin_bit_cast(int, v),
                                        CTRL, 0xF, 0xF, true);
    return v + __builtin_bit_cast(float, r);
}
__device__ __forceinline__ float rowsum16(float v) {
    v = dpp_add<0x128>(v);
    v = dpp_add<0x124>(v);
    v = dpp_add<0x122>(v);
    v = dpp_add<0x121>(v);
    return v;
}

__device__ __forceinline__ float dot8f(half8v a, half8v b, float c) {
#if __has_builtin(__builtin_amdgcn_fdot2)
    half2v a0 = {a[0], a[1]}, b0 = {b[0], b[1]};
    half2v a1 = {a[2], a[3]}, b1 = {b[2], b[3]};
    half2v a2 = {a[4], a[5]}, b2 = {b[4], b[5]};
    half2v a3 = {a[6], a[7]}, b3 = {b[6], b[7]};
    c = __builtin_amdgcn_fdot2(a0, b0, c, false);
    c = __builtin_amdgcn_fdot2(a1, b1, c, false);
    c = __builtin_amdgcn_fdot2(a2, b2, c, false);
    c = __builtin_amdgcn_fdot2(a3, b3, c, false);
    return c;
#else
#pragma unroll
    for (int i = 0; i < 8; ++i) c += (float)a[i] * (float)b[i];
    return c;
#endif
}

// ---------------------------------------------------------------------------
// Kernel A: fused cross -> softmax -> wx partials. 512 thr, 2 blocks/CU.
// B2 map: cpart=t&15 (c-oct within 128-step), kg=(t>>4)&3 (k=kg+4j), wave w=t>>6 owns rows 4w..4w+3
// C  map: kq=t&7 (k=kq*4..+3), cg=t>>3 (c=cg*8..+7), all 32 rows
// ---------------------------------------------------------------------------
__global__ __launch_bounds__(TPB, 4) void enc_partial(
    const float* __restrict__ x, const float* __restrict__ cw,
    const float* __restrict__ sf, float* __restrict__ ws)
{
    extern __shared__ char smraw[];
    f16*   cwL  = (f16*)(smraw + SMB_CWL);
    f16*   xn   = (f16*)(smraw + SMB_XN);
    f16*   wt   = (f16*)(smraw + SMB_WT);
    float* xsqp = (float*)(smraw + SMB_F32);          // [8 waves][8 rows]
    float* wsp  = xsqp + 64;                          // [8][32] scratch / wsum partials
    float* cwsq = wsp + 256;                          // [32]

    const int t = threadIdx.x;
    const int b = blockIdx.y;
    const int w = t >> 6;
    const int l = t & 63;
    const int cpart = t & 15;
    const int kg    = (t >> 4) & 3;

    // ---- build cwL: cwL[s][j][lane] = cw[(l>>4)&3 + 4j][ (l&15)*8 + s*128 + e ] ----
    {
        for (int pi = 0; pi < 4; ++pi) {
            const int pair = w * 4 + pi;        // 0..31
            const int s = pair >> 3, j = pair & 7;
            const int k = ((l >> 4) & 3) + 4 * j;
            half8v v;
#pragma unroll
            for (int e = 0; e < 8; ++e) {
                const int c = (l & 15) * 8 + s * 128 + e;
                v[e] = (f16)cw[c * KK + k];
            }
            *reinterpret_cast<half8v*>(cwL + ((size_t)pair * 64 + l) * 8) = v;
        }
    }
    // ---- cwsq partials ----
    if (t < 256) {
        const int k = t & 31, part = t >> 5;
        float s = 0.f;
        for (int c = part * 64; c < part * 64 + 64; ++c) {
            const float v = cw[c * KK + k];
            s += v * v;
        }
        wsp[part * 32 + k] = s;
    }
    __syncthreads();
    if (t < 32) {
        float s = 0.f;
#pragma unroll
        for (int p = 0; p < 8; ++p) s += wsp[p * 32 + t];
        cwsq[t] = s;
    }
    __syncthreads();

    float nsf[8], cq[8];
#pragma unroll
    for (int j = 0; j < 8; ++j) {
        const int k = kg + 4 * j;
        nsf[j] = -sf[k];
        cq[j]  = cwsq[k];
    }

    const int kq = t & 7;
    const int cg = t >> 3;    // 0..63, c-oct = cg*8

    float2v acc2[4][4];
#pragma unroll
    for (int p = 0; p < 4; ++p)
#pragma unroll
        for (int k = 0; k < 4; ++k) acc2[p][k] = (float2v){0.f, 0.f};
    float wsacc[8] = {0.f, 0.f, 0.f, 0.f, 0.f, 0.f, 0.f, 0.f};

    const int n0base = blockIdx.x * CHUNK;
    for (int tile = 0; tile < CHUNK / 32; ++tile) {
        const int n0 = n0base + tile * 32;

        // ---- stage 32x512 fp32 -> f16 LDS; exact fp32 x_sq on the fly ----
        float sqp[8];
#pragma unroll
        for (int i = 0; i < 8; ++i) {
            const int f  = i * TPB + t;
            const int rr = f >> 7;
            const int c4 = (f & 127) << 2;
            const float4 v = *reinterpret_cast<const float4*>(
                x + (size_t)(b * NN + n0 + rr) * CCH + c4);
            sqp[i] = v.x * v.x + v.y * v.y + v.z * v.z + v.w * v.w;
            half4v h = {(f16)v.x, (f16)v.y, (f16)v.z, (f16)v.w};
            *reinterpret_cast<half4v*>(xn + rr * XPH + c4) = h;
        }
#pragma unroll
        for (int i = 0; i < 8; ++i) {
            float v = sqp[i];
            v += __shfl_xor(v, 1);  v += __shfl_xor(v, 2);
            v += __shfl_xor(v, 4);  v += __shfl_xor(v, 8);
            v += __shfl_xor(v, 16); v += __shfl_xor(v, 32);
            if (l == 0) xsqp[w * 8 + i] = v;   // row = 4i + (w>>1)
        }
        __syncthreads();

        // ---- B2: cross via fdot2; wave w handles rows 4w..4w+3 ----
        float cr[4][8];
#pragma unroll
        for (int q = 0; q < 4; ++q)
#pragma unroll
            for (int j = 0; j < 8; ++j) cr[q][j] = 0.f;

        for (int s = 0; s < 4; ++s) {
            half8v xv[4];
#pragma unroll
            for (int q = 0; q < 4; ++q)
                xv[q] = *reinterpret_cast<const half8v*>(
                    xn + (w * 4 + q) * XPH + s * 128 + cpart * 8);
#pragma unroll
            for (int j = 0; j < 8; ++j) {
                const half8v cv = *reinterpret_cast<const half8v*>(
                    cwL + ((size_t)(s * 8 + j) * 64 + l) * 8);
#pragma unroll
                for (int q = 0; q < 4; ++q) cr[q][j] = dot8f(xv[q], cv, cr[q][j]);
            }
        }
#pragma unroll
        for (int q = 0; q < 4; ++q)
#pragma unroll
            for (int j = 0; j < 8; ++j) cr[q][j] = rowsum16(cr[q][j]);

        // ---- softmax over 32 k ----
#pragma unroll
        for (int q = 0; q < 4; ++q) {
            const int r = w * 4 + q;
            const float xs = xsqp[(2 * (r & 3)) * 8 + (r >> 2)]
                           + xsqp[(2 * (r & 3) + 1) * 8 + (r >> 2)];
            float lg[8];
#pragma unroll
            for (int j = 0; j < 8; ++j)
                lg[j] = (xs - 2.f * cr[q][j] + cq[j]) * nsf[j];
            float m = lg[0];
#pragma unroll
            for (int j = 1; j < 8; ++j) m = fmaxf(m, lg[j]);
            m = fmaxf(m, __shfl_xor(m, 16));
            m = fmaxf(m, __shfl_xor(m, 32));
            float e[8], ssum = 0.f;
#pragma unroll
            for (int j = 0; j < 8; ++j) { e[j] = __expf(lg[j] - m); ssum += e[j]; }
            ssum += __shfl_xor(ssum, 16);
            ssum += __shfl_xor(ssum, 32);
            const float inv = 1.f / ssum;
            if (cpart == 0) {
#pragma unroll
                for (int j = 0; j < 8; ++j) {
                    const float wv = e[j] * inv;
                    wsacc[j] += wv;
                    wt[r * WPH + kg + 4 * j] = (f16)wv;
                }
            }
        }
        __syncthreads();   // wt ready

        // ---- C: wx[c][k] += w[n][k]*x[n][c], 8c x 4k per thread, all 32 rows ----
#pragma unroll 4
        for (int rr = 0; rr < 32; ++rr) {
            const half8v xv = *reinterpret_cast<const half8v*>(xn + rr * XPH + cg * 8);
            const half4v wv = *reinterpret_cast<const half4v*>(wt + rr * WPH + kq * 4);
            const float wk0 = (float)wv[0], wk1 = (float)wv[1];
            const float wk2 = (float)wv[2], wk3 = (float)wv[3];
#pragma unroll
            for (int p = 0; p < 4; ++p) {
                const float2v xf = {(float)xv[2 * p], (float)xv[2 * p + 1]};
                acc2[p][0] += xf * (float2v){wk0, wk0};
                acc2[p][1] += xf * (float2v){wk1, wk1};
                acc2[p][2] += xf * (float2v){wk2, wk2};
                acc2[p][3] += xf * (float2v){wk3, wk3};
            }
        }
        __syncthreads();   // protect xn/wt before next tile
    }

    // ---- epilogue: atomics ----
    {
        float* wx = ws + WS_WX + (size_t)b * CCH * KK;
#pragma unroll
        for (int p = 0; p < 4; ++p)
#pragma unroll
            for (int k = 0; k < 4; ++k) {
                atomicAdd(&wx[(cg * 8 + 2 * p) * KK + kq * 4 + k], acc2[p][k][0]);
                atomicAdd(&wx[(cg * 8 + 2 * p + 1) * KK + kq * 4 + k], acc2[p][k][1]);
            }
    }
    if (cpart == 0) {
#pragma unroll
        for (int j = 0; j < 8; ++j) wsp[w * 32 + kg + 4 * j] = wsacc[j];
    }
    __syncthreads();
    if (t < 32) {
        float s = 0.f;
#pragma unroll
        for (int p = 0; p < 8; ++p) s += wsp[p * 32 + t];
        atomicAdd(&ws[WS_WSUM + b * KK + t], s);
    }
}

// ---------------------------------------------------------------------------
// Kernel B1: enc -> BN -> ReLU -> sum_k  => encv[b][c]
// ---------------------------------------------------------------------------
__global__ __launch_bounds__(256) void encv_kernel(
    float* __restrict__ ws, const float* __restrict__ cw,
    const float* __restrict__ gamma, const float* __restrict__ beta,
    const float* __restrict__ mean, const float* __restrict__ var)
{
    __shared__ float wsum_s[KK];
    const int b = blockIdx.x;
    const int t = threadIdx.x;
    if (t < KK) wsum_s[t] = ws[WS_WSUM + b * KK + t];
    __syncthreads();
    for (int c = t; c < CCH; c += 256) {
        const float g  = gamma[c] * rsqrtf(var[c] + BN_EPS);
        const float mu = mean[c];
        const float be = beta[c];
        const float* wxr = ws + WS_WX + (size_t)(b * CCH + c) * KK;
        const float* cwr = cw + c * KK;
        float s = 0.f;
#pragma unroll
        for (int k4 = 0; k4 < KK; k4 += 4) {
            const float4 wv = *reinterpret_cast<const float4*>(wxr + k4);
            const float4 cv = *reinterpret_cast<const float4*>(cwr + k4);
            const float4 sv = *reinterpret_cast<const float4*>(&wsum_s[k4]);
            s += fmaxf((wv.x - cv.x * sv.x - mu) * g + be, 0.f);
            s += fmaxf((wv.y - cv.y * sv.y - mu) * g + be, 0.f);
            s += fmaxf((wv.z - cv.z * sv.z - mu) * g + be, 0.f);
            s += fmaxf((wv.w - cv.w * sv.w - mu) * g + be, 0.f);
        }
        ws[WS_ENC + b * CCH + c] = s;
    }
}

// ---------------------------------------------------------------------------
// Kernel B2: attn = sigmoid(encv @ w_enc + b_enc) ; se = sigmoid(encv @ w_se + b_se)
// ---------------------------------------------------------------------------
__global__ __launch_bounds__(256) void attn_se_kernel(
    float* __restrict__ ws, const float* __restrict__ w_enc,
    const float* __restrict__ b_enc, const float* __restrict__ w_se,
    const float* __restrict__ b_se, float* __restrict__ out)
{
    __shared__ float ev[CCH];
    __shared__ float red[4][64];
    const int b   = blockIdx.y;
    const int cgb = blockIdx.x;
    const int t   = threadIdx.x;
    ev[t]       = ws[WS_ENC + b * CCH + t];
    ev[t + 256] = ws[WS_ENC + b * CCH + 256 + t];
    __syncthreads();
    if (cgb < 8) {
        const int c2 = cgb * 64 + (t & 63);
        const int p  = t >> 6;
        float a = 0.f;
#pragma unroll 4
        for (int i = 0; i < 128; ++i) {
            const int c = p * 128 + i;
            a += ev[c] * w_enc[c * CCH + c2];
        }
        red[p][t & 63] = a;
        __syncthreads();
        if (t < 64) {
            const float v = red[0][t] + red[1][t] + red[2][t] + red[3][t]
                          + b_enc[cgb * 64 + t];
            ws[WS_ATTN + b * CCH + cgb * 64 + t] = 1.f / (1.f + __expf(-v));
        }
    } else if (t < 8 * CLS) {
        const int j = t >> 3, p = t & 7;
        float a = 0.f;
        for (int c = p; c < CCH; c += 8) a += ev[c] * w_se[c * CLS + j];
        a += __shfl_xor(a, 1);
        a += __shfl_xor(a, 2);
        a += __shfl_xor(a, 4);
        if (p == 0)
            out[(size_t)BB * NN * CCH + b * CLS + j] =
                1.f / (1.f + __expf(-(a + b_se[j])));
    }
}

// ---------------------------------------------------------------------------
// Kernel C: featuremaps = attn[b,c] * x
// ---------------------------------------------------------------------------
__global__ __launch_bounds__(256) void scale_out(
    const float* __restrict__ x, const float* __restrict__ ws,
    float* __restrict__ out)
{
    const int gid = blockIdx.x * 256 + threadIdx.x;
    const int c4  = (gid & 127) << 2;
#pragma unroll
    for (int b = 0; b < BB; ++b) {
        const size_t f = ((size_t)b << 19) + (size_t)gid;
        const float4 xv = *reinterpret_cast<const float4*>(x + 4 * f);
        const float4 av = *reinterpret_cast<const float4*>(ws + WS_ATTN + b * CCH + c4);
        float4 o;
        o.x = xv.x * av.x; o.y = xv.y * av.y; o.z = xv.z * av.z; o.w = xv.w * av.w;
        *reinterpret_cast<float4*>(out + 4 * f) = o;
    }
}

// ---------------------------------------------------------------------------
extern "C" void kernel_launch(void* const* d_in, const int* in_sizes, int n_in,
                              void* d_out, int out_size, void* d_ws, size_t ws_size,
                              hipStream_t stream)
{
    const float* x     = (const float*)d_in[0];
    const float* cw    = (const float*)d_in[1];
    const float* sf    = (const float*)d_in[2];
    const float* gamma = (const float*)d_in[3];
    const float* beta  = (const float*)d_in[4];
    const float* mean  = (const float*)d_in[5];
    const float* var   = (const float*)d_in[6];
    const float* w_enc = (const float*)d_in[7];
    const float* b_enc = (const float*)d_in[8];
    const float* w_se  = (const float*)d_in[9];
    const float* b_se  = (const float*)d_in[10];
    float* out = (float*)d_out;
    float* ws  = (float*)d_ws;

    hipMemsetAsync(d_ws, 0, (size_t)(WS_WSUM + BB * KK) * sizeof(float), stream);

    enc_partial<<<dim3(NBLK, BB), TPB, SM_BYTES, stream>>>(x, cw, sf, ws);
    encv_kernel<<<BB, 256, 0, stream>>>(ws, cw, gamma, beta, mean, var);
    attn_se_kernel<<<dim3(9, BB), 256, 0, stream>>>(ws, w_enc, b_enc, w_se, b_se, out);
    scale_out<<<2048, 256, 0, stream>>>(x, ws, out);
}